// Round 9
// baseline (613.841 us; speedup 1.0000x reference)
//
#include <hip/hip_runtime.h>
#include <hip/hip_bf16.h>
#include <math.h>

#define BATCH 128
#define SEQ   200
#define HID   1024
#define NH    4
#define DK    256
#define NF    101    // SEQ/2+1
#define LS    200
#define PD    256    // padded s / fidx / l dimension
#define IMOFF 128    // imag block column offset in spectral layout

typedef __attribute__((ext_vector_type(8))) short bf16x8;
typedef __attribute__((ext_vector_type(4))) float f32x4;

__device__ __forceinline__ unsigned short f2bf(float f) {
    union { float f; unsigned u; } v; v.f = f;
    unsigned r = v.u + 0x7fff + ((v.u >> 16) & 1);
    return (unsigned short)(r >> 16);
}
__device__ __forceinline__ float bf2f(unsigned short h) {
    union { unsigned u; float f; } v; v.u = ((unsigned)h) << 16;
    return v.f;
}

__device__ __forceinline__ void gld_lds16(const void* g, void* l) {
    __builtin_amdgcn_global_load_lds(
        (const __attribute__((address_space(1))) unsigned*)g,
        (__attribute__((address_space(3))) unsigned*)l, 16, 0, 0);
}

// T2 swizzle (16B granularity, involution). Conflict-free b128 reads.
#define KSWZ(row, c8) ((c8) ^ (((row) & 7) << 3))

// ---------------------------------------------------------------------------
// Tables 256x256, pad=0. NEW layout: imag block at rows/cols 128..228.
// F[fidx][s]: fidx<101: cos(2pi fidx s/200)/sq200; fidx in [128,229): -sin;
//             else 0. s>=200 -> 0.
// G[s][j]:    j<101: a_j cos(2pi j s/200)/sq200 (a=1 for j in {0,100} else 2);
//             j in [128,229): f=j-128, f in {0,100} ? 0 : -2 sin(..)/sq200;
//             else 0. s>=200 -> 0.
// ---------------------------------------------------------------------------
__global__ void init_tables_bf16(unsigned short* __restrict__ F, unsigned short* __restrict__ G) {
    int idx = blockIdx.x * 256 + threadIdx.x;
    const double inv = 0.07071067811865475244;
    const double PI2 = 6.283185307179586476925;
    {
        int fidx = idx >> 8, s = idx & 255;
        double v = 0.0;
        if (s < SEQ) {
            if (fidx < NF) {
                v = cos(PI2 * (double)((fidx * s) % SEQ) / (double)SEQ) * inv;
            } else if (fidx >= IMOFF && fidx < IMOFF + NF) {
                int f = fidx - IMOFF;
                v = -sin(PI2 * (double)((f * s) % SEQ) / (double)SEQ) * inv;
            }
        }
        F[idx] = f2bf((float)v);
    }
    {
        int s = idx >> 8, j = idx & 255;
        double v = 0.0;
        if (s < SEQ) {
            if (j < NF) {
                double al = (j == 0 || j == NF - 1) ? 1.0 : 2.0;
                v = al * cos(PI2 * (double)((j * s) % SEQ) / (double)SEQ) * inv;
            } else if (j >= IMOFF && j < IMOFF + NF) {
                int f = j - IMOFF;
                if (f != 0 && f != NF - 1)
                    v = -2.0 * sin(PI2 * (double)((f * s) % SEQ) / (double)SEQ) * inv;
            }
        }
        G[idx] = f2bf((float)v);
    }
}

__global__ void wtrans256(const float* __restrict__ src, unsigned short* __restrict__ dst) {
    int dout = blockIdx.x, din = threadIdx.x;
    dst[dout * 256 + din] = f2bf(src[din * 256 + dout]);
}

__global__ void w3pad(const float* __restrict__ src, unsigned short* __restrict__ dst) {
    int row = blockIdx.x, col = threadIdx.x;
    dst[row * 256 + col] = (row < LS) ? f2bf(src[row * 256 + col]) : (unsigned short)0;
}

__global__ void fconv(const float* __restrict__ src, unsigned short* __restrict__ dst, int n) {
    int i = blockIdx.x * 256 + threadIdx.x;
    if (i < n) dst[i] = f2bf(src[i]);
}

// ---------------------------------------------------------------------------
// Fused QKV projection: one 256^3 GEMM workgroup per (tensor, bh).
// A = wT (bf16, gld_lds), B = raw fp32 rows (reg-staged cvt, s>=200 -> 0).
// 64KB static LDS single-buffer -> 2 wg/CU. z = 3*512.
// C[sel][bh](d, s) bf16, ldc=256.
// ---------------------------------------------------------------------------
__global__ __launch_bounds__(512, 2)
void mgemm256f(const unsigned short* __restrict__ Wall,
               const float* __restrict__ Q, const float* __restrict__ Kt,
               const float* __restrict__ V, unsigned short* __restrict__ C0) {
    __shared__ unsigned short As[256 * 64];
    __shared__ unsigned short Bs[256 * 64];

    int bz = blockIdx.x;
    int sel = bz >> 9;
    int bh = bz & 511;
    int b = bh >> 2, h = bh & 3;
    const unsigned short* A = Wall + sel * 65536;
    const float* Bf = ((sel == 0) ? Q : (sel == 1) ? Kt : V) + (long)b * SEQ * HID + h * DK;
    unsigned short* Ch = C0 + (long)sel * 33554432 + (long)bh * PD * PD;

    int t = threadIdx.x;
    int lane = t & 63, wave = t >> 6;
    int wr = wave >> 2, wc = wave & 3;
    int la = lane & 15, hi = lane >> 4;
    int rsub = t >> 3;
    int c8 = (t & 7) * 8;

    f32x4 acc[8][4] = {};

    for (int k0 = 0; k0 < 256; k0 += 64) {
#pragma unroll
        for (int p = 0; p < 4; ++p) {
            int row = p * 64 + rsub;
            gld_lds16(A + (long)row * 256 + k0 + KSWZ(row, c8), &As[row * 64 + c8]);
        }
#pragma unroll
        for (int p = 0; p < 4; ++p) {
            int row = p * 64 + rsub;
            unsigned short tmp[8];
            if (row < SEQ) {
                const float4* s4 = reinterpret_cast<const float4*>(Bf + (long)row * HID + k0 + c8);
                float4 x0 = s4[0], x1 = s4[1];
                tmp[0] = f2bf(x0.x); tmp[1] = f2bf(x0.y); tmp[2] = f2bf(x0.z); tmp[3] = f2bf(x0.w);
                tmp[4] = f2bf(x1.x); tmp[5] = f2bf(x1.y); tmp[6] = f2bf(x1.z); tmp[7] = f2bf(x1.w);
            } else {
#pragma unroll
                for (int j = 0; j < 8; ++j) tmp[j] = 0;
            }
            *(bf16x8*)&Bs[row * 64 + KSWZ(row, c8)] = *(bf16x8*)tmp;
        }
        __syncthreads();
#pragma unroll
        for (int half = 0; half < 2; ++half) {
            int ko = half * 32 + hi * 8;
            bf16x8 bb[4], xx[8];
#pragma unroll
            for (int ni = 0; ni < 4; ++ni) {
                int rb = wc * 64 + ni * 16 + la;
                bb[ni] = *(const bf16x8*)&Bs[rb * 64 + KSWZ(rb, ko)];
            }
#pragma unroll
            for (int mi = 0; mi < 8; ++mi) {
                int ra = wr * 128 + mi * 16 + la;
                xx[mi] = *(const bf16x8*)&As[ra * 64 + KSWZ(ra, ko)];
            }
            __builtin_amdgcn_s_setprio(1);
#pragma unroll
            for (int mi = 0; mi < 8; ++mi)
#pragma unroll
                for (int ni = 0; ni < 4; ++ni)
                    acc[mi][ni] = __builtin_amdgcn_mfma_f32_16x16x32_bf16(xx[mi], bb[ni], acc[mi][ni], 0, 0, 0);
            __builtin_amdgcn_s_setprio(0);
        }
        __syncthreads();
    }

#pragma unroll
    for (int mi = 0; mi < 8; ++mi) {
#pragma unroll
        for (int ni = 0; ni < 4; ++ni) {
            int gn = wc * 64 + ni * 16 + la;
            int gmB = wr * 128 + mi * 16 + hi * 4;
#pragma unroll
            for (int rr = 0; rr < 4; ++rr)
                Ch[(long)(gmB + rr) * PD + gn] = f2bf(acc[mi][ni][rr]);
        }
    }
}

// ---------------------------------------------------------------------------
// 256x256-tile bf16 MFMA GEMM, 4-phase interleave (unchanged from round 7).
// EPI: 0 bf16; 2 relu(acc+biasN)->bf16; 4 (acc+biasN)->bf16.
// ---------------------------------------------------------------------------
template <int EPI, bool XCDSWZ>
__global__ __launch_bounds__(512, 2)
void mgemm256(const unsigned short* __restrict__ A, const unsigned short* __restrict__ B,
              unsigned short* __restrict__ C0, int K, int lda, int ldb, int ldc,
              long aOuter, long aInner, long bOuter, long bInner,
              long cOuter, long cInner, int nInner, int mValid,
              const float* __restrict__ biasN) {
    extern __shared__ unsigned short lds[];
    unsigned short* AsB = lds;
    unsigned short* BsB = lds + 32768;

    int bx = blockIdx.x, by = blockIdx.y;
    if (XCDSWZ) {
        int nwg = gridDim.x * gridDim.y;
        int flat = by * gridDim.x + bx;
        int cpx = nwg >> 3;
        int swz = (flat & 7) * cpx + (flat >> 3);
        bx = swz % gridDim.x; by = swz / gridDim.x;
    }
    int bz = blockIdx.z;
    int bo = bz / nInner, bi = bz - bo * nInner;
    const unsigned short* Ab = A + bo * aOuter + bi * aInner;
    const unsigned short* Bb = B + bo * bOuter + bi * bInner;

    int t = threadIdx.x;
    int m0 = by * 256, n0 = bx * 256;
    int lane = t & 63, wave = t >> 6;
    int wr = wave >> 2, wc = wave & 3;
    int la = lane & 15, hi = lane >> 4;

    f32x4 acc[8][4] = {};
    int rsub = t >> 3;
    int c8 = (t & 7) * 8;

    auto stageA = [&](unsigned short* dst, long k0, int h) {
#pragma unroll
        for (int p = 0; p < 2; ++p) {
            int row = h * 128 + p * 64 + rsub;
            gld_lds16(Ab + (long)(m0 + row) * lda + k0 + KSWZ(row, c8), &dst[row * 64 + c8]);
        }
    };
    auto stageB = [&](unsigned short* dst, long k0, int h) {
#pragma unroll
        for (int p = 0; p < 2; ++p) {
            int row = h * 128 + p * 64 + rsub;
            gld_lds16(Bb + (long)(n0 + row) * ldb + k0 + KSWZ(row, c8), &dst[row * 64 + c8]);
        }
    };
    auto ldf = [&](const unsigned short* P, int row, int ko) -> bf16x8 {
        return *(const bf16x8*)&P[row * 64 + KSWZ(row, ko)];
    };

#define MFMA_ROW(mi, xa) \
    acc[mi][0] = __builtin_amdgcn_mfma_f32_16x16x32_bf16(xa, b0, acc[mi][0], 0, 0, 0); \
    acc[mi][1] = __builtin_amdgcn_mfma_f32_16x16x32_bf16(xa, b1, acc[mi][1], 0, 0, 0); \
    acc[mi][2] = __builtin_amdgcn_mfma_f32_16x16x32_bf16(xa, b2, acc[mi][2], 0, 0, 0); \
    acc[mi][3] = __builtin_amdgcn_mfma_f32_16x16x32_bf16(xa, b3, acc[mi][3], 0, 0, 0);

    int nkt = K >> 6;
    stageA(AsB, 0, 0); stageA(AsB, 0, 1);
    stageB(BsB, 0, 0); stageB(BsB, 0, 1);

    for (int kt = 0; kt < nkt; ++kt) {
        int cur = kt & 1;
        const unsigned short* Ac = AsB + cur * 16384;
        const unsigned short* Bc = BsB + cur * 16384;
        unsigned short* An = AsB + (cur ^ 1) * 16384;
        unsigned short* Bn = BsB + (cur ^ 1) * 16384;
        bool pre = (kt + 1) < nkt;
        long kn = (long)(kt + 1) << 6;

        bf16x8 b0, b1, b2, b3;

        if (pre) {
            stageA(An, kn, 0);
            asm volatile("s_waitcnt vmcnt(2)" ::: "memory");
        } else {
            asm volatile("s_waitcnt vmcnt(0)" ::: "memory");
        }
        __builtin_amdgcn_s_barrier();
        __builtin_amdgcn_sched_barrier(0);
        {
            int ko = hi * 8;
            b0 = ldf(Bc, wc * 64 + 0 * 16 + la, ko);
            b1 = ldf(Bc, wc * 64 + 1 * 16 + la, ko);
            b2 = ldf(Bc, wc * 64 + 2 * 16 + la, ko);
            b3 = ldf(Bc, wc * 64 + 3 * 16 + la, ko);
            bf16x8 x0 = ldf(Ac, wr * 128 + 0 * 16 + la, ko);
            bf16x8 x1 = ldf(Ac, wr * 128 + 1 * 16 + la, ko);
            bf16x8 x2 = ldf(Ac, wr * 128 + 2 * 16 + la, ko);
            bf16x8 x3 = ldf(Ac, wr * 128 + 3 * 16 + la, ko);
            __builtin_amdgcn_s_setprio(1);
            MFMA_ROW(0, x0) MFMA_ROW(1, x1) MFMA_ROW(2, x2) MFMA_ROW(3, x3)
            __builtin_amdgcn_s_setprio(0);
        }
        __builtin_amdgcn_s_barrier();

        if (pre) stageA(An, kn, 1);
        {
            int ko = hi * 8;
            bf16x8 x4 = ldf(Ac, wr * 128 + 4 * 16 + la, ko);
            bf16x8 x5 = ldf(Ac, wr * 128 + 5 * 16 + la, ko);
            bf16x8 x6 = ldf(Ac, wr * 128 + 6 * 16 + la, ko);
            bf16x8 x7 = ldf(Ac, wr * 128 + 7 * 16 + la, ko);
            __builtin_amdgcn_s_setprio(1);
            MFMA_ROW(4, x4) MFMA_ROW(5, x5) MFMA_ROW(6, x6) MFMA_ROW(7, x7)
            __builtin_amdgcn_s_setprio(0);
        }
        __builtin_amdgcn_s_barrier();

        if (pre) stageB(Bn, kn, 0);
        {
            int ko = 32 + hi * 8;
            b0 = ldf(Bc, wc * 64 + 0 * 16 + la, ko);
            b1 = ldf(Bc, wc * 64 + 1 * 16 + la, ko);
            b2 = ldf(Bc, wc * 64 + 2 * 16 + la, ko);
            b3 = ldf(Bc, wc * 64 + 3 * 16 + la, ko);
            bf16x8 x0 = ldf(Ac, wr * 128 + 0 * 16 + la, ko);
            bf16x8 x1 = ldf(Ac, wr * 128 + 1 * 16 + la, ko);
            bf16x8 x2 = ldf(Ac, wr * 128 + 2 * 16 + la, ko);
            bf16x8 x3 = ldf(Ac, wr * 128 + 3 * 16 + la, ko);
            __builtin_amdgcn_s_setprio(1);
            MFMA_ROW(0, x0) MFMA_ROW(1, x1) MFMA_ROW(2, x2) MFMA_ROW(3, x3)
            __builtin_amdgcn_s_setprio(0);
        }
        __builtin_amdgcn_s_barrier();

        if (pre) stageB(Bn, kn, 1);
        {
            int ko = 32 + hi * 8;
            bf16x8 x4 = ldf(Ac, wr * 128 + 4 * 16 + la, ko);
            bf16x8 x5 = ldf(Ac, wr * 128 + 5 * 16 + la, ko);
            bf16x8 x6 = ldf(Ac, wr * 128 + 6 * 16 + la, ko);
            bf16x8 x7 = ldf(Ac, wr * 128 + 7 * 16 + la, ko);
            __builtin_amdgcn_s_setprio(1);
            MFMA_ROW(4, x4) MFMA_ROW(5, x5) MFMA_ROW(6, x6) MFMA_ROW(7, x7)
            __builtin_amdgcn_s_setprio(0);
        }
        __builtin_amdgcn_s_barrier();
    }
#undef MFMA_ROW

    unsigned short* Ch = C0 + bo * cOuter + bi * cInner;
#pragma unroll
    for (int mi = 0; mi < 8; ++mi) {
#pragma unroll
        for (int ni = 0; ni < 4; ++ni) {
            int gn = n0 + wc * 64 + ni * 16 + la;
            int gmB = m0 + wr * 128 + mi * 16 + hi * 4;
            float bN = 0.f;
            if (EPI == 2 || EPI == 4) bN = biasN[gn];
#pragma unroll
            for (int rr = 0; rr < 4; ++rr) {
                int gm = gmB + rr;
                if (gm >= mValid) continue;
                float v = acc[mi][ni][rr];
                if (EPI == 0) Ch[(long)gm * ldc + gn] = f2bf(v);
                else if (EPI == 2) Ch[(long)gm * ldc + gn] = f2bf(fmaxf(v + bN, 0.f));
                else Ch[(long)gm * ldc + gn] = f2bf(v + bN);
            }
        }
    }
}

// ---------------------------------------------------------------------------
// Fused alphaT GEMM + softmax-over-s. One 512-thread wg per bh computes the
// full 256x256 (l,s) plane (A=w3b, B=corr, K=256), then: row-max/exp/row-sum
// over s (shfl within 16-lane groups + 4KB cross-wave LDS), writes probs bf16
// via LDS bounce (coalesced 16B stores). Pad cols s>=200 -> 0.
// ---------------------------------------------------------------------------
__global__ __launch_bounds__(512, 2)
void alphasm(const unsigned short* __restrict__ A, const unsigned short* __restrict__ B,
             unsigned short* __restrict__ P0) {
    extern __shared__ unsigned short lds[];
    unsigned short* AsB = lds;
    unsigned short* BsB = lds + 32768;
    __shared__ float redM[256][4];
    __shared__ float redS[256][4];

    int bh = blockIdx.x;
    const unsigned short* Ab = A;
    const unsigned short* Bb = B + (long)bh * PD * PD;

    int t = threadIdx.x;
    int lane = t & 63, wave = t >> 6;
    int wr = wave >> 2, wc = wave & 3;
    int la = lane & 15, hi = lane >> 4;

    f32x4 acc[8][4] = {};
    int rsub = t >> 3;
    int c8 = (t & 7) * 8;

    auto stageA = [&](unsigned short* dst, long k0, int h) {
#pragma unroll
        for (int p = 0; p < 2; ++p) {
            int row = h * 128 + p * 64 + rsub;
            gld_lds16(Ab + (long)row * PD + k0 + KSWZ(row, c8), &dst[row * 64 + c8]);
        }
    };
    auto stageB = [&](unsigned short* dst, long k0, int h) {
#pragma unroll
        for (int p = 0; p < 2; ++p) {
            int row = h * 128 + p * 64 + rsub;
            gld_lds16(Bb + (long)row * PD + k0 + KSWZ(row, c8), &dst[row * 64 + c8]);
        }
    };
    auto ldf = [&](const unsigned short* P, int row, int ko) -> bf16x8 {
        return *(const bf16x8*)&P[row * 64 + KSWZ(row, ko)];
    };

#define MFMA_ROW(mi, xa) \
    acc[mi][0] = __builtin_amdgcn_mfma_f32_16x16x32_bf16(xa, b0, acc[mi][0], 0, 0, 0); \
    acc[mi][1] = __builtin_amdgcn_mfma_f32_16x16x32_bf16(xa, b1, acc[mi][1], 0, 0, 0); \
    acc[mi][2] = __builtin_amdgcn_mfma_f32_16x16x32_bf16(xa, b2, acc[mi][2], 0, 0, 0); \
    acc[mi][3] = __builtin_amdgcn_mfma_f32_16x16x32_bf16(xa, b3, acc[mi][3], 0, 0, 0);

    stageA(AsB, 0, 0); stageA(AsB, 0, 1);
    stageB(BsB, 0, 0); stageB(BsB, 0, 1);

    for (int kt = 0; kt < 4; ++kt) {
        int cur = kt & 1;
        const unsigned short* Ac = AsB + cur * 16384;
        const unsigned short* Bc = BsB + cur * 16384;
        unsigned short* An = AsB + (cur ^ 1) * 16384;
        unsigned short* Bn = BsB + (cur ^ 1) * 16384;
        bool pre = kt < 3;
        long kn = (long)(kt + 1) << 6;
        bf16x8 b0, b1, b2, b3;

        if (pre) {
            stageA(An, kn, 0);
            asm volatile("s_waitcnt vmcnt(2)" ::: "memory");
        } else {
            asm volatile("s_waitcnt vmcnt(0)" ::: "memory");
        }
        __builtin_amdgcn_s_barrier();
        __builtin_amdgcn_sched_barrier(0);
        {
            int ko = hi * 8;
            b0 = ldf(Bc, wc * 64 + 0 * 16 + la, ko);
            b1 = ldf(Bc, wc * 64 + 1 * 16 + la, ko);
            b2 = ldf(Bc, wc * 64 + 2 * 16 + la, ko);
            b3 = ldf(Bc, wc * 64 + 3 * 16 + la, ko);
            bf16x8 x0 = ldf(Ac, wr * 128 + 0 * 16 + la, ko);
            bf16x8 x1 = ldf(Ac, wr * 128 + 1 * 16 + la, ko);
            bf16x8 x2 = ldf(Ac, wr * 128 + 2 * 16 + la, ko);
            bf16x8 x3 = ldf(Ac, wr * 128 + 3 * 16 + la, ko);
            __builtin_amdgcn_s_setprio(1);
            MFMA_ROW(0, x0) MFMA_ROW(1, x1) MFMA_ROW(2, x2) MFMA_ROW(3, x3)
            __builtin_amdgcn_s_setprio(0);
        }
        __builtin_amdgcn_s_barrier();
        if (pre) stageA(An, kn, 1);
        {
            int ko = hi * 8;
            bf16x8 x4 = ldf(Ac, wr * 128 + 4 * 16 + la, ko);
            bf16x8 x5 = ldf(Ac, wr * 128 + 5 * 16 + la, ko);
            bf16x8 x6 = ldf(Ac, wr * 128 + 6 * 16 + la, ko);
            bf16x8 x7 = ldf(Ac, wr * 128 + 7 * 16 + la, ko);
            __builtin_amdgcn_s_setprio(1);
            MFMA_ROW(4, x4) MFMA_ROW(5, x5) MFMA_ROW(6, x6) MFMA_ROW(7, x7)
            __builtin_amdgcn_s_setprio(0);
        }
        __builtin_amdgcn_s_barrier();
        if (pre) stageB(Bn, kn, 0);
        {
            int ko = 32 + hi * 8;
            b0 = ldf(Bc, wc * 64 + 0 * 16 + la, ko);
            b1 = ldf(Bc, wc * 64 + 1 * 16 + la, ko);
            b2 = ldf(Bc, wc * 64 + 2 * 16 + la, ko);
            b3 = ldf(Bc, wc * 64 + 3 * 16 + la, ko);
            bf16x8 x0 = ldf(Ac, wr * 128 + 0 * 16 + la, ko);
            bf16x8 x1 = ldf(Ac, wr * 128 + 1 * 16 + la, ko);
            bf16x8 x2 = ldf(Ac, wr * 128 + 2 * 16 + la, ko);
            bf16x8 x3 = ldf(Ac, wr * 128 + 3 * 16 + la, ko);
            __builtin_amdgcn_s_setprio(1);
            MFMA_ROW(0, x0) MFMA_ROW(1, x1) MFMA_ROW(2, x2) MFMA_ROW(3, x3)
            __builtin_amdgcn_s_setprio(0);
        }
        __builtin_amdgcn_s_barrier();
        if (pre) stageB(Bn, kn, 1);
        {
            int ko = 32 + hi * 8;
            bf16x8 x4 = ldf(Ac, wr * 128 + 4 * 16 + la, ko);
            bf16x8 x5 = ldf(Ac, wr * 128 + 5 * 16 + la, ko);
            bf16x8 x6 = ldf(Ac, wr * 128 + 6 * 16 + la, ko);
            bf16x8 x7 = ldf(Ac, wr * 128 + 7 * 16 + la, ko);
            __builtin_amdgcn_s_setprio(1);
            MFMA_ROW(4, x4) MFMA_ROW(5, x5) MFMA_ROW(6, x6) MFMA_ROW(7, x7)
            __builtin_amdgcn_s_setprio(0);
        }
        __builtin_amdgcn_s_barrier();
    }
#undef MFMA_ROW

    // ---- softmax over s (cols gn), per row gm = l ----
    // pass 1: row maxes (masked gn < LS)
#pragma unroll
    for (int mi = 0; mi < 8; ++mi) {
#pragma unroll
        for (int rr = 0; rr < 4; ++rr) {
            float mv = -1e30f;
#pragma unroll
            for (int ni = 0; ni < 4; ++ni) {
                int gn = wc * 64 + ni * 16 + la;
                if (gn < LS) mv = fmaxf(mv, acc[mi][ni][rr]);
            }
            mv = fmaxf(mv, __shfl_xor(mv, 1));
            mv = fmaxf(mv, __shfl_xor(mv, 2));
            mv = fmaxf(mv, __shfl_xor(mv, 4));
            mv = fmaxf(mv, __shfl_xor(mv, 8));
            if (la == 0) redM[wr * 128 + mi * 16 + hi * 4 + rr][wc] = mv;
        }
    }
    __syncthreads();
    // pass 2: exp + row sums
#pragma unroll
    for (int mi = 0; mi < 8; ++mi) {
#pragma unroll
        for (int rr = 0; rr < 4; ++rr) {
            int row = wr * 128 + mi * 16 + hi * 4 + rr;
            float m = fmaxf(fmaxf(redM[row][0], redM[row][1]),
                            fmaxf(redM[row][2], redM[row][3]));
            float s = 0.f;
#pragma unroll
            for (int ni = 0; ni < 4; ++ni) {
                int gn = wc * 64 + ni * 16 + la;
                float e = (gn < LS) ? __expf(acc[mi][ni][rr] - m) : 0.f;
                acc[mi][ni][rr] = e;
                s += e;
            }
            s += __shfl_xor(s, 1);
            s += __shfl_xor(s, 2);
            s += __shfl_xor(s, 4);
            s += __shfl_xor(s, 8);
            if (la == 0) redS[row][wc] = s;
        }
    }
    __syncthreads();
    // pass 3: normalize, scatter to LDS plane
    unsigned short* P = lds;   // 256x256 bf16 = 128KB (staging buffers dead)
#pragma unroll
    for (int mi = 0; mi < 8; ++mi) {
#pragma unroll
        for (int rr = 0; rr < 4; ++rr) {
            int row = wr * 128 + mi * 16 + hi * 4 + rr;
            float inv = 1.f / (redS[row][0] + redS[row][1] + redS[row][2] + redS[row][3]);
#pragma unroll
            for (int ni = 0; ni < 4; ++ni) {
                int gn = wc * 64 + ni * 16 + la;
                P[row * 256 + gn] = f2bf(acc[mi][ni][rr] * inv);
            }
        }
    }
    __syncthreads();
    // coalesced copy out
    unsigned short* Pg = P0 + (long)bh * PD * PD;
    for (int i = t; i < 256 * 32; i += 512) {
        int row = i >> 5, seg = (i & 31) * 8;
        *(bf16x8*)(Pg + (long)row * PD + seg) = *(const bf16x8*)&P[row * 256 + seg];
    }
}

// ---------------------------------------------------------------------------
// Vectorized cross-spectrum * complex weight, IN PLACE on QF.
// Layout (bh, d, 256): re cols [0,101), im cols [128,229). 16B-aligned bf16x8.
// One block per bh; thread loop over (d, fg) with fg in [0,13).
// ---------------------------------------------------------------------------
__global__ __launch_bounds__(256)
void crossspec(unsigned short* __restrict__ QF, const unsigned short* __restrict__ KF,
               const float* __restrict__ cw) {
    int bh = blockIdx.x;
    int h = bh & (NH - 1);
    long qbase = (long)bh * DK * PD;
    for (int i = threadIdx.x; i < DK * 13; i += 256) {
        int d = i / 13, fg = i - d * 13;
        long rb = qbase + (long)d * PD + fg * 8;
        bf16x8 qre = *(const bf16x8*)(QF + rb);
        bf16x8 qim = *(const bf16x8*)(QF + rb + IMOFF);
        bf16x8 kre = *(const bf16x8*)(KF + rb);
        bf16x8 kim = *(const bf16x8*)(KF + rb + IMOFF);
        bf16x8 orr, oii;
#pragma unroll
        for (int j = 0; j < 8; ++j) {
            int f = fg * 8 + j;
            float qr = bf2f((unsigned short)qre[j]), qi = bf2f((unsigned short)qim[j]);
            float kr = bf2f((unsigned short)kre[j]), ki = bf2f((unsigned short)kim[j]);
            float cr = qr * kr + qi * ki;
            float ci = qi * kr - qr * ki;
            float wr = 0.f, wi = 0.f;
            if (f < NF) {
                long wb = (((long)h * NF + f) * DK + d) * 2;
                wr = cw[wb]; wi = cw[wb + 1];
            }
            orr[j] = (short)f2bf(cr * wr - ci * wi);
            oii[j] = (short)f2bf(cr * wi + ci * wr);
        }
        *(bf16x8*)(QF + rb) = orr;
        *(bf16x8*)(QF + rb + IMOFF) = oii;
    }
}

// ---------------------------------------------------------------------------
// gelu(erf) + TF LayerNorm per 1024-wide row (bf16 in, fp32 out)
// ---------------------------------------------------------------------------
__global__ __launch_bounds__(256) void gelu_ln_kernel(const unsigned short* __restrict__ y2,
                               const float* __restrict__ lnw, const float* __restrict__ lnb,
                               float* __restrict__ out) {
    long row = blockIdx.x;
    int tid = threadIdx.x;
    const short4* xr = reinterpret_cast<const short4*>(y2 + row * HID);
    short4 h4 = xr[tid];
    float g[4];
    {
        float x0 = bf2f((unsigned short)h4.x), x1 = bf2f((unsigned short)h4.y);
        float x2 = bf2f((unsigned short)h4.z), x3 = bf2f((unsigned short)h4.w);
        g[0] = 0.5f * x0 * (1.f + erff(x0 * 0.70710678118654752f));
        g[1] = 0.5f * x1 * (1.f + erff(x1 * 0.70710678118654752f));
        g[2] = 0.5f * x2 * (1.f + erff(x2 * 0.70710678118654752f));
        g[3] = 0.5f * x3 * (1.f + erff(x3 * 0.70710678118654752f));
    }

    __shared__ float red[4];
    float s = g[0] + g[1] + g[2] + g[3];
#pragma unroll
    for (int o = 32; o > 0; o >>= 1) s += __shfl_down(s, o);
    if ((tid & 63) == 0) red[tid >> 6] = s;
    __syncthreads();
    float mean = (red[0] + red[1] + red[2] + red[3]) * (1.f / (float)HID);

    float v2 = 0.f;
#pragma unroll
    for (int p = 0; p < 4; ++p) { float d = g[p] - mean; v2 += d * d; }
    __syncthreads();
#pragma unroll
    for (int o = 32; o > 0; o >>= 1) v2 += __shfl_down(v2, o);
    if ((tid & 63) == 0) red[tid >> 6] = v2;
    __syncthreads();
    float var = (red[0] + red[1] + red[2] + red[3]) * (1.f / (float)HID);
    float rstd = rsqrtf(var + 1e-12f);

    float4 o4;
    int i0 = tid * 4;
    o4.x = (g[0] - mean) * rstd * lnw[i0 + 0] + lnb[i0 + 0];
    o4.y = (g[1] - mean) * rstd * lnw[i0 + 1] + lnb[i0 + 1];
    o4.z = (g[2] - mean) * rstd * lnw[i0 + 2] + lnb[i0 + 2];
    o4.w = (g[3] - mean) * rstd * lnw[i0 + 3] + lnb[i0 + 3];
    reinterpret_cast<float4*>(out + row * HID)[tid] = o4;
}

// ---------------------------------------------------------------------------
extern "C" void kernel_launch(void* const* d_in, const int* in_sizes, int n_in,
                              void* d_out, int out_size, void* d_ws, size_t ws_size,
                              hipStream_t stream) {
    const float* query = (const float*)d_in[0];
    const float* key   = (const float*)d_in[1];
    const float* value = (const float*)d_in[2];
    const float* w0 = (const float*)d_in[3];
    const float* w1 = (const float*)d_in[4];
    const float* w2 = (const float*)d_in[5];
    const float* w3 = (const float*)d_in[6];
    const float* attn_bias = (const float*)d_in[7];
    const float* cw = (const float*)d_in[8];
    const float* lw = (const float*)d_in[9];
    const float* lb = (const float*)d_in[10];
    const float* lnw = (const float*)d_in[11];
    const float* lnb = (const float*)d_in[12];
    float* out = (float*)d_out;

    char* base = (char*)d_ws;
    const long BH = (long)BATCH * NH;
    const long SZR = (long)BH * PD * PD;          // elements per 64MiB bf16 region
    const size_t M64 = 67108864;

    unsigned short* F_stack = (unsigned short*)(base + 0);
    unsigned short* G_stack = (unsigned short*)(base + 131072);
    unsigned short* w0T = (unsigned short*)(base + 262144);   // w0T/w1T/w2T contiguous
    unsigned short* w3b = (unsigned short*)(base + 655360);
    unsigned short* lwb = (unsigned short*)(base + 786432);   // 2MiB
    char* rA = base + 4194304;            // qpT -> corr
    char* rB = rA + M64;                  // kpT -> probs
    char* rC = rB + M64;                  // vpT
    char* rD = rC + M64;                  // QF/R -> y2(bf16)
    char* rE = rD + M64;                  // KF   -> X

    unsigned short* qpT = (unsigned short*)rA;   // proj writes qpT,kpT,vpT contiguous
    unsigned short* kpT = (unsigned short*)rB;
    unsigned short* vpT = (unsigned short*)rC;
    unsigned short* QF  = (unsigned short*)rD;
    unsigned short* KF  = (unsigned short*)rE;
    unsigned short* corr = (unsigned short*)rA;
    unsigned short* probs = (unsigned short*)rB;
    unsigned short* X  = (unsigned short*)rE;
    unsigned short* y2 = (unsigned short*)rD;

    const size_t LDS256 = 131072;

    // tables + weight conversion
    init_tables_bf16<<<256, 256, 0, stream>>>(F_stack, G_stack);
    wtrans256<<<256, 256, 0, stream>>>(w0, w0T);
    wtrans256<<<256, 256, 0, stream>>>(w1, w0T + 65536);
    wtrans256<<<256, 256, 0, stream>>>(w2, w0T + 131072);
    w3pad<<<256, 256, 0, stream>>>(w3, w3b);
    fconv<<<(HID * HID + 255) / 256, 256, 0, stream>>>(lw, lwb, HID * HID);

    // fused QKV projections: one wg per (tensor, bh); query read once
    mgemm256f<<<dim3(3 * 512, 1, 1), 512, 0, stream>>>(w0T, query, key, value, qpT);

    // forward DFT (q and k batched via bo): QF[bh](d,f) = qpT @ F^T
    mgemm256<0, false><<<dim3(1, 1, 2 * BH), 512, LDS256, stream>>>(
        qpT, F_stack, QF, PD, PD, PD, PD,
        SZR, (long)PD * PD, 0L, 0L, SZR, (long)PD * PD, (int)BH, PD, nullptr);

    // cross-spectrum * weight (vectorized, in place on QF)
    crossspec<<<(unsigned)BH, 256, 0, stream>>>(QF, KF, cw);

    // inverse DFT: corr[bh](s,d) = G @ R^T, epilogue relu(+attn_bias over d)
    mgemm256<2, false><<<dim3(1, 1, BH), 512, LDS256, stream>>>(
        G_stack, QF, corr, PD, PD, PD, PD,
        0L, 0L, (long)PD * PD, 0L, (long)PD * PD, 0L, 1, PD, attn_bias);

    // fused alphaT + softmax -> probs
    alphasm<<<dim3((unsigned)BH, 1, 1), 512, LDS256, stream>>>(w3b, corr, probs);

    // X[b, l, h*256+d] = probs(l,s) @ vpT(d,s)^T
    mgemm256<0, false><<<dim3(1, 1, BH), 512, LDS256, stream>>>(
        probs, vpT, X, PD, PD, PD, HID,
        (long)NH * PD * PD, (long)PD * PD,
        (long)NH * PD * PD, (long)PD * PD,
        (long)LS * HID, (long)DK, NH, LS, nullptr);

    // y2 = X @ lw^T + lb : 25600 x 1024 x 1024  (bf16 out, XCD swizzle)
    mgemm256<4, true><<<dim3(HID / 256, (BATCH * LS) / 256, 1), 512, LDS256, stream>>>(
        X, lwb, y2, HID, HID, HID, HID,
        0L, 0L, 0L, 0L, 0L, 0L, 1, BATCH * LS, lb);

    // gelu + LayerNorm
    gelu_ln_kernel<<<(unsigned)(BATCH * LS), 256, 0, stream>>>(y2, lnw, lnb, out);
}